// Round 5
// baseline (279.434 us; speedup 1.0000x reference)
//
#include <hip/hip_runtime.h>
#include <hip/hip_bf16.h>
#include <math.h>

#define NN 50000
#define NNP 50048        // padded rows: 391 * 128
#define NE 800000
#define NB 391           // buckets of 128 nodes
#define EPB 6250         // edges per bscat block (128 blocks)

typedef short bf16x8 __attribute__((ext_vector_type(8)));
typedef float f32x4 __attribute__((ext_vector_type(4)));
typedef float f32x2 __attribute__((ext_vector_type(2)));
typedef unsigned short us4 __attribute__((ext_vector_type(4)));
typedef unsigned short us8 __attribute__((ext_vector_type(8)));
typedef unsigned int u32x4 __attribute__((ext_vector_type(4)));

__device__ __forceinline__ float bf2f(unsigned short u) {
  union { unsigned int i; float f; } x; x.i = ((unsigned int)u) << 16; return x.f;
}
__device__ __forceinline__ float u2f(unsigned int u) {
  union { unsigned int i; float f; } x; x.i = u; return x.f;
}
__device__ __forceinline__ unsigned short f2bf(float f) {
  union { float f; unsigned int i; } x; x.f = f;
  unsigned int i = x.i;
  unsigned int r = i + 0x7FFF + ((i >> 16) & 1);   // round-to-nearest-even
  return (unsigned short)(r >> 16);
}
__device__ __forceinline__ unsigned long long pk64(f32x4 v) {
  union { us4 s; unsigned long long u; } x;
  x.s[0] = f2bf(v[0]); x.s[1] = f2bf(v[1]); x.s[2] = f2bf(v[2]); x.s[3] = f2bf(v[3]);
  return x.u;
}
__device__ __forceinline__ bf16x8 bfrag(const unsigned short* __restrict__ Bp, int idx, int lane) {
  return *(const bf16x8*)(Bp + (size_t)idx * 512 + lane * 8);
}

// ---------------- inclusive scan over 512 threads (in LDS) ---------------------
__device__ __forceinline__ int scan_incl_512(int v, int* s) {
  int t = threadIdx.x;
  s[t] = v; __syncthreads();
  for (int off = 1; off < 512; off <<= 1) {
    int x = (t >= off) ? s[t - off] : 0;
    __syncthreads();
    s[t] += x;
    __syncthreads();
  }
  return s[t];
}

// ---------------- bucket scatter (scan of bhist inlined per block) -------------
__global__ __launch_bounds__(512) void bscat_kernel(const int* __restrict__ srcn,
                                                    const int* __restrict__ dstn,
                                                    const int* __restrict__ bhist,
                                                    int* __restrict__ gcur,
                                                    unsigned long long* __restrict__ ebuf) {
  __shared__ int sbuf[512];
  __shared__ int boff[NB];
  __shared__ int hist[NB];
  __shared__ int base[NB];
  int t = threadIdx.x;
  int v = (t < NB) ? bhist[t] : 0;
  int incl = scan_incl_512(v, sbuf);
  if (t < NB) { boff[t] = incl - v; hist[t] = 0; }
  __syncthreads();
  int e0 = blockIdx.x * EPB;
  for (int i = t; i < EPB; i += 512)
    atomicAdd(&hist[dstn[e0 + i] >> 7], 1);
  __syncthreads();
  for (int i = t; i < NB; i += 512) {
    int c = hist[i];
    base[i] = c ? (boff[i] + atomicAdd(&gcur[i], c)) : 0;
  }
  __syncthreads();
  for (int i = t; i < EPB; i += 512) {
    int s = srcn[e0 + i], d = dstn[e0 + i];
    int b = d >> 7;
    int pos = atomicSub(&hist[b], 1) - 1;   // order within slice irrelevant
    ebuf[(size_t)base[b] + pos] = ((unsigned long long)(unsigned)d << 32) | (unsigned)s;
  }
}

// ---------------- per-bucket counting sort -> CSR (scan inlined) ---------------
__global__ __launch_bounds__(512) void bfill_kernel(const unsigned long long* __restrict__ ebuf,
                                                    const int* __restrict__ bhist,
                                                    int* __restrict__ rowoff,
                                                    int* __restrict__ csr) {
  __shared__ int sbuf[512];
  __shared__ int sb[2];
  __shared__ int ndeg[128], noff[128];
  int b = blockIdx.x;
  int t = threadIdx.x;
  int v = (t < NB) ? bhist[t] : 0;
  int incl = scan_incl_512(v, sbuf);
  if (t == b) { sb[0] = incl - v; sb[1] = v; }
  if (t < 128) ndeg[t] = 0;
  __syncthreads();
  int bo = sb[0], cnt = sb[1];
  for (int i = t; i < cnt; i += 512)
    atomicAdd(&ndeg[(int)(ebuf[bo + i] >> 32) & 127], 1);
  __syncthreads();
  if (t < 128) noff[t] = ndeg[t];
  __syncthreads();
  for (int off = 1; off < 128; off <<= 1) {   // inclusive scan (Hillis-Steele)
    int x = 0;
    if (t < 128 && t >= off) x = noff[t - off];
    __syncthreads();
    if (t < 128 && t >= off) noff[t] += x;
    __syncthreads();
  }
  if (t < 128) {
    int ex = noff[t] - ndeg[t];    // exclusive
    noff[t] = ex;
    int node = b * 128 + t;
    if (node < NN) rowoff[node] = bo + ex;
  }
  if (b == NB - 1 && t == 0) rowoff[NN] = NE;
  __syncthreads();
  for (int i = t; i < cnt; i += 512) {
    unsigned long long e = ebuf[bo + i];
    int dl = (int)(e >> 32) & 127;
    int pos = atomicSub(&ndeg[dl], 1) - 1;
    csr[bo + noff[dl] + pos] = (int)(unsigned)e;
  }
}

// ---------------- fused setup: convz (6250 blocks) | prep (64) | bhist (128) ----
__global__ __launch_bounds__(256) void setup_kernel(
    const float* __restrict__ z, unsigned short* __restrict__ A1,
    const float* __restrict__ w1n, const float* __restrict__ w1r,
    const float* __restrict__ w2n, const float* __restrict__ w2r,
    const float* __restrict__ wfn, const float* __restrict__ wfr,
    const float* __restrict__ wr1, const float* __restrict__ wr2,
    unsigned short* __restrict__ Bp1, unsigned short* __restrict__ Bp2,
    unsigned short* __restrict__ Bp3,
    const int* __restrict__ dstn, int* __restrict__ bhist) {
  __shared__ int h[NB];
  int b = blockIdx.x;
  if (b < 6250) {               // ---- convz: z (f32) -> bf16 into A1 right half
    int i = b * 256 + threadIdx.x;
    if (i >= NN * 128 / 4) return;
    int i4 = i * 4;
    int row = i4 >> 7, c = i4 & 127;
    f32x4 v = *(const f32x4*)(z + i4);
    us4 o = { f2bf(v[0]), f2bf(v[1]), f2bf(v[2]), f2bf(v[3]) };
    *(us4*)(A1 + (size_t)row * 256 + 128 + c) = o;
  } else if (b < 6314) {        // ---- prep: pack B into MFMA fragment-major
    int g = (b - 6250) * 256 + threadIdx.x;
    unsigned short* D; int NT, fi;
    int which;  // 1,2,3
    if      (g < 10240) { fi = g;         D = Bp1; NT = 20; which = 1; }
    else if (g < 14336) { fi = g - 10240; D = Bp2; NT = 8;  which = 2; }
    else if (g < 16384) { fi = g - 14336; D = Bp3; NT = 4;  which = 3; }
    else return;
    int lane = fi & 63, t = fi >> 6;
    int nt = t % NT, k0i = t / NT;
    int m = lane & 15, q = lane >> 4;
    int kb = k0i * 32 + q * 8;          // 8-aligned: all j on same side of 128
    int n = nt * 16 + m;
    int hi = (kb >= 128);
    int k0_ = kb - (hi ? 128 : 0);
    const float* W = nullptr; int Nseg = 128; int nn = n;
    if (which == 1) {
      if (n < 128)      { W = hi ? w1r : w1n; nn = n; Nseg = 128; }
      else if (n < 256) { W = hi ? wr1 : nullptr; nn = n - 128; Nseg = 128; }
      else              { W = hi ? wr2 : nullptr; nn = n - 256; Nseg = 64; }
    } else if (which == 2) { W = hi ? w2r : w2n; Nseg = 128; }
    else                   { W = hi ? wfr : wfn; Nseg = 64; }
    unsigned short o[8];
#pragma unroll
    for (int j = 0; j < 8; j++)
      o[j] = W ? f2bf(W[(size_t)(k0_ + j) * Nseg + nn]) : (unsigned short)0;
    *(us8*)(D + (size_t)fi * 8) = *(const us8*)o;
  } else {                      // ---- bhist
    for (int i = threadIdx.x; i < NB; i += 256) h[i] = 0;
    __syncthreads();
    int e0 = (b - 6314) * EPB;
    for (int i = threadIdx.x; i < EPB; i += 256)
      atomicAdd(&h[dstn[e0 + i] >> 7], 1);
    __syncthreads();
    for (int i = threadIdx.x; i < NB; i += 256)
      if (h[i]) atomicAdd(&bhist[i], h[i]);
  }
}

// ---------------- pair gather: one wave aggregates nodes (n0, n0+1) ------------
// 8 row-loads in flight per wave (vs 4 single-node). feat rows are 256B at
// stride 512B; all loads clamped+weight-predicated (handles deg 0 and tails).
__device__ __forceinline__ void agg_wave2(const unsigned short* __restrict__ feat,
                                          unsigned short* __restrict__ outm,
                                          const int* __restrict__ rowoff,
                                          const int* __restrict__ csr, int n0) {
  int lane = threadIdx.x & 63;
  int g = lane >> 4;           // neighbor subgroup 0..3
  int c = (lane & 15) << 3;    // column offset (8 bf16 = 16B per lane)
  int begA = rowoff[n0], begB = rowoff[n0 + 1], endB = rowoff[n0 + 2];
  int endA = begB;
  f32x2 aA[4], aB[4];
#pragma unroll
  for (int k = 0; k < 4; ++k) { aA[k] = (f32x2){0.f, 0.f}; aB[k] = (f32x2){0.f, 0.f}; }
  int e1A = endA - 1 > begA ? endA - 1 : begA;   // safe clamp target (valid index)
  int e1B = endB - 1 > begB ? endB - 1 : begB;
  if (e1A >= NE) e1A = NE - 1;
  if (e1B >= NE) e1B = NE - 1;
  int jA = begA + g, jB = begB + g;
  while (jA < endA || jB < endB) {
    int iA0 = jA      < e1A ? jA      : e1A;
    int iA1 = jA + 4  < e1A ? jA + 4  : e1A;
    int iA2 = jA + 8  < e1A ? jA + 8  : e1A;
    int iA3 = jA + 12 < e1A ? jA + 12 : e1A;
    int iB0 = jB      < e1B ? jB      : e1B;
    int iB1 = jB + 4  < e1B ? jB + 4  : e1B;
    int iB2 = jB + 8  < e1B ? jB + 8  : e1B;
    int iB3 = jB + 12 < e1B ? jB + 12 : e1B;
    int sA0 = csr[iA0], sA1 = csr[iA1], sA2 = csr[iA2], sA3 = csr[iA3];
    int sB0 = csr[iB0], sB1 = csr[iB1], sB2 = csr[iB2], sB3 = csr[iB3];
    float wA0 = (jA      < endA) ? 1.f : 0.f;
    float wA1 = (jA + 4  < endA) ? 1.f : 0.f;
    float wA2 = (jA + 8  < endA) ? 1.f : 0.f;
    float wA3 = (jA + 12 < endA) ? 1.f : 0.f;
    float wB0 = (jB      < endB) ? 1.f : 0.f;
    float wB1 = (jB + 4  < endB) ? 1.f : 0.f;
    float wB2 = (jB + 8  < endB) ? 1.f : 0.f;
    float wB3 = (jB + 12 < endB) ? 1.f : 0.f;
    u32x4 vA0 = *(const u32x4*)(feat + (size_t)sA0 * 256 + c);
    u32x4 vA1 = *(const u32x4*)(feat + (size_t)sA1 * 256 + c);
    u32x4 vA2 = *(const u32x4*)(feat + (size_t)sA2 * 256 + c);
    u32x4 vA3 = *(const u32x4*)(feat + (size_t)sA3 * 256 + c);
    u32x4 vB0 = *(const u32x4*)(feat + (size_t)sB0 * 256 + c);
    u32x4 vB1 = *(const u32x4*)(feat + (size_t)sB1 * 256 + c);
    u32x4 vB2 = *(const u32x4*)(feat + (size_t)sB2 * 256 + c);
    u32x4 vB3 = *(const u32x4*)(feat + (size_t)sB3 * 256 + c);
#pragma unroll
    for (int k = 0; k < 4; ++k) {
      aA[k] += (f32x2){u2f(vA0[k] << 16), u2f(vA0[k] & 0xffff0000u)} * wA0;
      aA[k] += (f32x2){u2f(vA1[k] << 16), u2f(vA1[k] & 0xffff0000u)} * wA1;
      aA[k] += (f32x2){u2f(vA2[k] << 16), u2f(vA2[k] & 0xffff0000u)} * wA2;
      aA[k] += (f32x2){u2f(vA3[k] << 16), u2f(vA3[k] & 0xffff0000u)} * wA3;
      aB[k] += (f32x2){u2f(vB0[k] << 16), u2f(vB0[k] & 0xffff0000u)} * wB0;
      aB[k] += (f32x2){u2f(vB1[k] << 16), u2f(vB1[k] & 0xffff0000u)} * wB1;
      aB[k] += (f32x2){u2f(vB2[k] << 16), u2f(vB2[k] & 0xffff0000u)} * wB2;
      aB[k] += (f32x2){u2f(vB3[k] << 16), u2f(vB3[k] & 0xffff0000u)} * wB3;
    }
    jA += 16; jB += 16;
  }
#pragma unroll
  for (int k = 0; k < 4; ++k)
#pragma unroll
    for (int h2 = 0; h2 < 2; ++h2) {
      aA[k][h2] += __shfl_xor(aA[k][h2], 16, 64);
      aA[k][h2] += __shfl_xor(aA[k][h2], 32, 64);
      aB[k][h2] += __shfl_xor(aB[k][h2], 16, 64);
      aB[k][h2] += __shfl_xor(aB[k][h2], 32, 64);
    }
  if (g == 0) {
    float invA = 1.f / fmaxf((float)(endA - begA), 1.f);
    float invB = 1.f / fmaxf((float)(endB - begB), 1.f);
    unsigned int oA[4], oB[4];
#pragma unroll
    for (int k = 0; k < 4; ++k) {
      oA[k] = ((unsigned int)f2bf(aA[k][1] * invA) << 16) | f2bf(aA[k][0] * invA);
      oB[k] = ((unsigned int)f2bf(aB[k][1] * invB) << 16) | f2bf(aB[k][0] * invB);
    }
    *(u32x4*)(outm + (size_t)n0 * 256 + c) = *(const u32x4*)oA;
    *(u32x4*)(outm + (size_t)(n0 + 1) * 256 + c) = *(const u32x4*)oB;
  }
}

__global__ __launch_bounds__(512, 4) void agg_kernel(unsigned short* __restrict__ A,
                                                     const int* __restrict__ rowoff,
                                                     const int* __restrict__ csr) {
  int n0 = (blockIdx.x * 8 + (threadIdx.x >> 6)) * 2;
  agg_wave2(A + 128, A, rowoff, csr, n0);
}

// ---------------- 64-col gather (layer 3): y3 rows are 128B at stride 512B -----
__device__ __forceinline__ void agg64_wave(const unsigned short* __restrict__ feat,
                                           unsigned short* __restrict__ outm,
                                           const int* __restrict__ rowoff,
                                           const int* __restrict__ csr, int node) {
  int lane = threadIdx.x & 63;
  int g = lane >> 3;           // neighbor subgroup 0..7
  int c = (lane & 7) << 3;     // column offset (8 bf16 = 16B per lane)
  int beg = rowoff[node], end = rowoff[node + 1];
  f32x2 a[4];
#pragma unroll
  for (int k = 0; k < 4; ++k) a[k] = (f32x2){0.f, 0.f};
  int e1 = end - 1 > beg ? end - 1 : beg;
  if (e1 >= NE) e1 = NE - 1;
  for (int j = beg + g; j < end; j += 32) {
    int j1 = (j + 8  < e1) ? j + 8  : e1;
    int j2 = (j + 16 < e1) ? j + 16 : e1;
    int j3 = (j + 24 < e1) ? j + 24 : e1;
    int s0 = csr[j], s1 = csr[j1], s2 = csr[j2], s3 = csr[j3];
    float w1 = (j + 8  < end) ? 1.f : 0.f;
    float w2 = (j + 16 < end) ? 1.f : 0.f;
    float w3 = (j + 24 < end) ? 1.f : 0.f;
    u32x4 v0 = *(const u32x4*)(feat + (size_t)s0 * 256 + c);
    u32x4 v1 = *(const u32x4*)(feat + (size_t)s1 * 256 + c);
    u32x4 v2 = *(const u32x4*)(feat + (size_t)s2 * 256 + c);
    u32x4 v3 = *(const u32x4*)(feat + (size_t)s3 * 256 + c);
#pragma unroll
    for (int k = 0; k < 4; ++k) {
      a[k] += (f32x2){u2f(v0[k] << 16), u2f(v0[k] & 0xffff0000u)};
      a[k] += (f32x2){u2f(v1[k] << 16), u2f(v1[k] & 0xffff0000u)} * w1;
      a[k] += (f32x2){u2f(v2[k] << 16), u2f(v2[k] & 0xffff0000u)} * w2;
      a[k] += (f32x2){u2f(v3[k] << 16), u2f(v3[k] & 0xffff0000u)} * w3;
    }
  }
#pragma unroll
  for (int k = 0; k < 4; ++k)
#pragma unroll
    for (int h2 = 0; h2 < 2; ++h2) {
      a[k][h2] += __shfl_xor(a[k][h2], 8, 64);
      a[k][h2] += __shfl_xor(a[k][h2], 16, 64);
      a[k][h2] += __shfl_xor(a[k][h2], 32, 64);
    }
  if (g == 0) {
    float inv = 1.f / fmaxf((float)(end - beg), 1.f);
    unsigned int o[4];
#pragma unroll
    for (int k = 0; k < 4; ++k)
      o[k] = ((unsigned int)f2bf(a[k][1] * inv) << 16) | f2bf(a[k][0] * inv);
    *(u32x4*)(outm + (size_t)node * 256 + c) = *(const u32x4*)o;
  }
}

// agg3: gather y3 (A1 left, cols 64..127) -> mean3y (A1 left, cols 0..63)
__global__ __launch_bounds__(512, 8) void agg64_kernel(unsigned short* __restrict__ A1,
                                                       const int* __restrict__ rowoff,
                                                       const int* __restrict__ csr) {
  int node = blockIdx.x * 8 + (threadIdx.x >> 6);
  agg64_wave(A1 + 64, A1, rowoff, csr, node);
}

// ---------------- agg1 (pairs) + res gemm merged -------------------------------
__global__ __launch_bounds__(512, 4) void aggres1_kernel(
    unsigned short* __restrict__ A1,
    const unsigned short* __restrict__ Bp1,
    const float* __restrict__ br1, const float* __restrict__ br2,
    const int* __restrict__ rowoff, const int* __restrict__ csr,
    unsigned short* __restrict__ res1, unsigned short* __restrict__ res2) {
  int bx = blockIdx.x;
  if (bx < 3125) {
    int n0 = (bx * 8 + (threadIdx.x >> 6)) * 2;
    agg_wave2(A1 + 128, A1, rowoff, csr, n0);
    return;
  }
  int b = bx - 3125;                 // 0..781
  int chunk = (b >= NB);             // 0: tiles 8..13, 1: tiles 14..19
  int bb = b - chunk * NB;
  int tid = threadIdx.x;
  int w = tid >> 6, lane = tid & 63;
  int m = lane & 15, q = lane >> 4;
  int row = bb * 128 + w * 16 + m;
  const unsigned short* ar = A1 + (size_t)row * 256 + 128 + q * 8;
  bf16x8 af[4];
#pragma unroll
  for (int k = 0; k < 4; ++k) af[k] = *(const bf16x8*)(ar + k * 32);
  f32x4 acc[6];
#pragma unroll
  for (int t = 0; t < 6; ++t) acc[t] = (f32x4){0.f, 0.f, 0.f, 0.f};
#pragma unroll
  for (int k0i = 0; k0i < 4; ++k0i)
#pragma unroll
    for (int t = 0; t < 6; ++t)
      acc[t] = __builtin_amdgcn_mfma_f32_16x16x32_bf16(
          bfrag(Bp1, (k0i + 4) * 20 + 8 + chunk * 6 + t, lane), af[k0i], acc[t], 0, 0, 0);
  int src0 = m + ((q & 1) ? 32 : 0);
#pragma unroll
  for (int pl = 0; pl < 3; ++pl) {
    int P = chunk * 3 + pl;
    const float* bias; unsigned short* dst; int dstride, colb;
    if (P < 4) { bias = br1 + 32 * P;       dst = res1; dstride = 128; colb = 32 * P; }
    else       { bias = br2 + 32 * (P - 4); dst = res2; dstride = 64;  colb = 32 * (P - 4); }
    f32x4 v0 = acc[2 * pl], v1 = acc[2 * pl + 1];
    f32x4 bb0 = *(const f32x4*)(bias + 4 * q);
    f32x4 bb1 = *(const f32x4*)(bias + 16 + 4 * q);
#pragma unroll
    for (int r = 0; r < 4; ++r) { v0[r] += bb0[r]; v1[r] += bb1[r]; }
    unsigned long long d0 = pk64(v0), d1 = pk64(v1);
    unsigned long long a0 = __shfl(d0, src0, 64);
    unsigned long long b0 = __shfl(d0, src0 + 16, 64);
    unsigned long long a1 = __shfl(d1, src0, 64);
    unsigned long long b1v = __shfl(d1, src0 + 16, 64);
    unsigned long long lo = (q >> 1) ? a1 : a0;
    unsigned long long hi = (q >> 1) ? b1v : b0;
    unsigned long long ov[2] = { lo, hi };
    *(us8*)(dst + (size_t)row * dstride + colb + 8 * q) = *(const us8*)ov;  // res padded NNP
  }
}

// ---------------- gemm1h: [mean1|z] @ W1-pack tiles 0..7 -> h1 (A2 right) ------
__global__ __launch_bounds__(256, 4) void gemm1h_kernel(
    const unsigned short* __restrict__ A1,
    const unsigned short* __restrict__ Bp1,
    const float* __restrict__ b1,
    unsigned short* __restrict__ A2) {
  int tid = threadIdx.x;
  int w = tid >> 6, lane = tid & 63;
  int m = lane & 15, q = lane >> 4;
  int row = blockIdx.x * 64 + w * 16 + m;
  const unsigned short* ar = A1 + (size_t)row * 256 + q * 8;
  bf16x8 af[8];
#pragma unroll
  for (int k = 0; k < 8; ++k) af[k] = *(const bf16x8*)(ar + k * 32);
  f32x4 acc[8];
#pragma unroll
  for (int t = 0; t < 8; ++t) acc[t] = (f32x4){0.f, 0.f, 0.f, 0.f};
#pragma unroll
  for (int k0i = 0; k0i < 8; ++k0i)
#pragma unroll
    for (int t = 0; t < 8; ++t)
      acc[t] = __builtin_amdgcn_mfma_f32_16x16x32_bf16(
          bfrag(Bp1, k0i * 20 + t, lane), af[k0i], acc[t], 0, 0, 0);
  int src0 = m + ((q & 1) ? 32 : 0);
#pragma unroll
  for (int p = 0; p < 4; ++p) {
    f32x4 v0 = acc[2 * p], v1 = acc[2 * p + 1];
    f32x4 bb0 = *(const f32x4*)(b1 + 32 * p + 4 * q);
    f32x4 bb1 = *(const f32x4*)(b1 + 32 * p + 16 + 4 * q);
#pragma unroll
    for (int r = 0; r < 4; ++r) {
      v0[r] = fmaxf(v0[r] + bb0[r], 0.f);
      v1[r] = fmaxf(v1[r] + bb1[r], 0.f);
    }
    unsigned long long d0 = pk64(v0), d1 = pk64(v1);
    unsigned long long a0 = __shfl(d0, src0, 64);
    unsigned long long b0 = __shfl(d0, src0 + 16, 64);
    unsigned long long a1 = __shfl(d1, src0, 64);
    unsigned long long b1v = __shfl(d1, src0 + 16, 64);
    unsigned long long lo = (q >> 1) ? a1 : a0;
    unsigned long long hi = (q >> 1) ? b1v : b0;
    unsigned long long ov[2] = { lo, hi };
    *(us8*)(A2 + (size_t)row * 256 + 128 + 32 * p + 8 * q) = *(const us8*)ov;
  }
}

// ---------------- gemm2: [mean2|h1] @ W2 + res1 -> h2 (A1 right); fused y3 -----
// y3 = h2 @ wfn (mean-side tiles of Bp3): A-frags are exactly the epilogue's ov
// bytes. y3 lands in A1 left half cols 64..127 (dead region).
__global__ __launch_bounds__(256, 4) void gemm2_kernel(
    const unsigned short* __restrict__ A2,
    const unsigned short* __restrict__ Bp2,
    const unsigned short* __restrict__ Bp3,
    const float* __restrict__ b2,
    const unsigned short* __restrict__ res1,
    unsigned short* __restrict__ A1out) {
  int tid = threadIdx.x;
  int w = tid >> 6, lane = tid & 63;
  int m = lane & 15, q = lane >> 4;
  int row = blockIdx.x * 64 + w * 16 + m;
  const unsigned short* ar = A2 + (size_t)row * 256 + q * 8;
  bf16x8 af[8];
#pragma unroll
  for (int k = 0; k < 8; ++k) af[k] = *(const bf16x8*)(ar + k * 32);
  f32x4 acc[8];
#pragma unroll
  for (int t = 0; t < 8; ++t) acc[t] = (f32x4){0.f, 0.f, 0.f, 0.f};
#pragma unroll
  for (int k0i = 0; k0i < 8; ++k0i)
#pragma unroll
    for (int t = 0; t < 8; ++t)
      acc[t] = __builtin_amdgcn_mfma_f32_16x16x32_bf16(
          bfrag(Bp2, k0i * 8 + t, lane), af[k0i], acc[t], 0, 0, 0);
  int src0 = m + ((q & 1) ? 32 : 0);
  bf16x8 afy[4];
#pragma unroll
  for (int p = 0; p < 4; ++p) {
    f32x4 v0 = acc[2 * p], v1 = acc[2 * p + 1];
    f32x4 bb0 = *(const f32x4*)(b2 + 32 * p + 4 * q);
    f32x4 bb1 = *(const f32x4*)(b2 + 32 * p + 16 + 4 * q);
#pragma unroll
    for (int r = 0; r < 4; ++r) {
      v0[r] = fmaxf(v0[r] + bb0[r], 0.f);
      v1[r] = fmaxf(v1[r] + bb1[r], 0.f);
    }
    unsigned long long d0 = pk64(v0), d1 = pk64(v1);
    unsigned long long a0 = __shfl(d0, src0, 64);
    unsigned long long b0 = __shfl(d0, src0 + 16, 64);
    unsigned long long a1 = __shfl(d1, src0, 64);
    unsigned long long b1v = __shfl(d1, src0 + 16, 64);
    unsigned long long lo = (q >> 1) ? a1 : a0;
    unsigned long long hi = (q >> 1) ? b1v : b0;
    size_t off = 32 * p + 8 * q;
    us8 rv = *(const us8*)(res1 + (size_t)row * 128 + off);   // res1 padded NNP
    unsigned long long ov[2] = { lo, hi };
    unsigned short* e = (unsigned short*)ov;
#pragma unroll
    for (int r = 0; r < 8; ++r) e[r] = f2bf(bf2f(e[r]) + bf2f(rv[r]));
    *(us8*)(A1out + (size_t)row * 256 + 128 + off) = *(const us8*)ov;
    afy[p] = *(const bf16x8*)ov;        // h2 fragment for y3 (k0i = p)
  }
  // y3 = h2 @ wfn : mean-side tiles of Bp3 (k0i*4 + t, k0i=0..3, t=0..3)
  f32x4 accy[4];
#pragma unroll
  for (int t = 0; t < 4; ++t) accy[t] = (f32x4){0.f, 0.f, 0.f, 0.f};
#pragma unroll
  for (int p = 0; p < 4; ++p)
#pragma unroll
    for (int t = 0; t < 4; ++t)
      accy[t] = __builtin_amdgcn_mfma_f32_16x16x32_bf16(
          bfrag(Bp3, p * 4 + t, lane), afy[p], accy[t], 0, 0, 0);
#pragma unroll
  for (int py = 0; py < 2; ++py) {
    f32x4 v0 = accy[2 * py], v1 = accy[2 * py + 1];
    unsigned long long d0 = pk64(v0), d1 = pk64(v1);
    unsigned long long a0 = __shfl(d0, src0, 64);
    unsigned long long b0 = __shfl(d0, src0 + 16, 64);
    unsigned long long a1 = __shfl(d1, src0, 64);
    unsigned long long b1v = __shfl(d1, src0 + 16, 64);
    unsigned long long lo = (q >> 1) ? a1 : a0;
    unsigned long long hi = (q >> 1) ? b1v : b0;
    unsigned long long ov[2] = { lo, hi };
    *(us8*)(A1out + (size_t)row * 256 + 64 + 32 * py + 8 * q) = *(const us8*)ov;
  }
}

// ---------------- gemm3: root side only + mean3y add, sigmoid cols 0..7 --------
__global__ __launch_bounds__(256, 4) void gemm3_kernel(
    const unsigned short* __restrict__ A1,
    const unsigned short* __restrict__ Bp3,
    const float* __restrict__ bias,
    const unsigned short* __restrict__ res2,
    float* __restrict__ out_f) {
  int tid = threadIdx.x;
  int w = tid >> 6, lane = tid & 63;
  int m = lane & 15, q = lane >> 4;
  int row = blockIdx.x * 64 + w * 16 + m;
  const unsigned short* ar = A1 + (size_t)row * 256 + 128 + q * 8;   // h2
  bf16x8 af[4];
#pragma unroll
  for (int k = 0; k < 4; ++k) af[k] = *(const bf16x8*)(ar + k * 32);
  f32x4 acc[4];
#pragma unroll
  for (int t = 0; t < 4; ++t) acc[t] = (f32x4){0.f, 0.f, 0.f, 0.f};
#pragma unroll
  for (int k0i = 0; k0i < 4; ++k0i)
#pragma unroll
    for (int t = 0; t < 4; ++t)
      acc[t] = __builtin_amdgcn_mfma_f32_16x16x32_bf16(
          bfrag(Bp3, (k0i + 4) * 4 + t, lane), af[k0i], acc[t], 0, 0, 0);
  if (row >= NN) return;
  int cb = q * 4;
#pragma unroll
  for (int s = 0; s < 4; ++s) {
    int col = s * 16 + cb;
    f32x4 v = acc[s];
    f32x4 bb = *(const f32x4*)(bias + col);
    us4 rv = *(const us4*)(res2 + (size_t)row * 64 + col);
    us4 mv = *(const us4*)(A1 + (size_t)row * 256 + col);   // mean3y
#pragma unroll
    for (int r = 0; r < 4; ++r) v[r] += bb[r] + bf2f(rv[r]) + bf2f(mv[r]);
    if (col < 8) {
#pragma unroll
      for (int r = 0; r < 4; ++r) v[r] = 1.f / (1.f + __expf(-v[r]));
    }
    *(f32x4*)(out_f + (size_t)row * 64 + col) = v;
  }
}

extern "C" void kernel_launch(void* const* d_in, const int* in_sizes, int n_in,
                              void* d_out, int out_size, void* d_ws, size_t ws_size,
                              hipStream_t stream) {
  const float* z   = (const float*)d_in[0];
  const int*   edge = (const int*)d_in[1];
  const int*   srcn = edge;        // edge_index[0]
  const int*   dstn = edge + NE;   // edge_index[1]
  const float* w1n = (const float*)d_in[2];
  const float* w1r = (const float*)d_in[3];
  const float* b1  = (const float*)d_in[4];
  const float* w2n = (const float*)d_in[5];
  const float* w2r = (const float*)d_in[6];
  const float* b2  = (const float*)d_in[7];
  const float* wfn = (const float*)d_in[8];
  const float* wfr = (const float*)d_in[9];
  const float* bfb = (const float*)d_in[10];
  const float* wr1 = (const float*)d_in[11];
  const float* br1 = (const float*)d_in[12];
  const float* wr2 = (const float*)d_in[13];
  const float* br2 = (const float*)d_in[14];
  float* out = (float*)d_out;

  char* p = (char*)d_ws;
  auto alloc = [&](size_t bytes) { char* r = p; p += (bytes + 255) & ~255ull; return r; };
  int* rowoff = (int*)alloc((size_t)(NN + 1) * 4);
  int* bhist  = (int*)alloc((size_t)2 * NB * 4);
  int* gcur   = bhist + NB;
  int* csr    = (int*)alloc((size_t)NE * 4);
  unsigned short* A1 = (unsigned short*)alloc((size_t)NNP * 256 * 2);  // [mean1|z] -> [mean3y,y3|h2]
  unsigned short* A2 = (unsigned short*)alloc((size_t)NNP * 256 * 2);  // [mean2|h1]
  unsigned short* res1 = (unsigned short*)alloc((size_t)NNP * 128 * 2);
  unsigned short* res2 = (unsigned short*)alloc((size_t)NNP * 64 * 2);
  unsigned short* Bp1 = (unsigned short*)alloc(10240 * 8 * 2);
  unsigned short* Bp2 = (unsigned short*)alloc(4096 * 8 * 2);
  unsigned short* Bp3 = (unsigned short*)alloc(2048 * 8 * 2);
  // ebuf aliases res1 (6.4 MB <= 12.8 MB): dead before aggres1 writes res1
  unsigned long long* ebuf = (unsigned long long*)res1;

  hipMemsetAsync(bhist, 0, (size_t)2 * NB * 4, stream);   // bhist + gcur
  // fused prologue: convz | prep | bhist
  setup_kernel<<<6442, 256, 0, stream>>>(z, A1, w1n, w1r, w2n, w2r, wfn, wfr, wr1, wr2,
                                         Bp1, Bp2, Bp3, dstn, bhist);
  bscat_kernel<<<128, 512, 0, stream>>>(srcn, dstn, bhist, gcur, ebuf);
  bfill_kernel<<<NB, 512, 0, stream>>>(ebuf, bhist, rowoff, csr);

  const int ggemm = NNP / 64;   // 782

  // layer 1: pair-gather(z) || res1/res2 root-gemm, then h1
  aggres1_kernel<<<3125 + 2 * NB, 512, 0, stream>>>(A1, Bp1, br1, br2, rowoff, csr, res1, res2);
  gemm1h_kernel<<<ggemm, 256, 0, stream>>>(A1, Bp1, b1, A2);

  // layer 2: pair-gather(h1); gemm2 writes h2 + fused y3 = h2@wfn
  agg_kernel<<<3125, 512, 0, stream>>>(A2, rowoff, csr);
  gemm2_kernel<<<ggemm, 256, 0, stream>>>(A2, Bp2, Bp3, b2, res1, A1);

  // layer 3: 64-col gather of y3 -> mean3y, then root gemm + adds
  agg64_kernel<<<6250, 512, 0, stream>>>(A1, rowoff, csr);
  gemm3_kernel<<<ggemm, 256, 0, stream>>>(A1, Bp3, bfb, res2, out);
}

// Round 7
// 279.068 us; speedup vs baseline: 1.0013x; 1.0013x over previous
//
#include <hip/hip_runtime.h>
#include <hip/hip_bf16.h>
#include <math.h>

#define NN 50000
#define NNP 50048        // padded rows: 391 * 128
#define NE 800000
#define NB 391           // buckets of 128 nodes
#define EPB 6250         // edges per bscat block (128 blocks)

typedef short bf16x8 __attribute__((ext_vector_type(8)));
typedef float f32x4 __attribute__((ext_vector_type(4)));
typedef float f32x2 __attribute__((ext_vector_type(2)));
typedef unsigned short us4 __attribute__((ext_vector_type(4)));
typedef unsigned short us8 __attribute__((ext_vector_type(8)));
typedef unsigned int u32x4 __attribute__((ext_vector_type(4)));

__device__ __forceinline__ float bf2f(unsigned short u) {
  union { unsigned int i; float f; } x; x.i = ((unsigned int)u) << 16; return x.f;
}
__device__ __forceinline__ float u2f(unsigned int u) {
  union { unsigned int i; float f; } x; x.i = u; return x.f;
}
__device__ __forceinline__ unsigned short f2bf(float f) {
  union { float f; unsigned int i; } x; x.f = f;
  unsigned int i = x.i;
  unsigned int r = i + 0x7FFF + ((i >> 16) & 1);   // round-to-nearest-even
  return (unsigned short)(r >> 16);
}
__device__ __forceinline__ unsigned long long pk64(f32x4 v) {
  union { us4 s; unsigned long long u; } x;
  x.s[0] = f2bf(v[0]); x.s[1] = f2bf(v[1]); x.s[2] = f2bf(v[2]); x.s[3] = f2bf(v[3]);
  return x.u;
}
__device__ __forceinline__ bf16x8 bfrag(const unsigned short* __restrict__ Bp, int idx, int lane) {
  return *(const bf16x8*)(Bp + (size_t)idx * 512 + lane * 8);
}

// ---------------- inclusive scan over 512 threads (in LDS) ---------------------
__device__ __forceinline__ int scan_incl_512(int v, int* s) {
  int t = threadIdx.x;
  s[t] = v; __syncthreads();
  for (int off = 1; off < 512; off <<= 1) {
    int x = (t >= off) ? s[t - off] : 0;
    __syncthreads();
    s[t] += x;
    __syncthreads();
  }
  return s[t];
}

// ---------------- bucket scatter (scan of bhist inlined per block) -------------
__global__ __launch_bounds__(512) void bscat_kernel(const int* __restrict__ srcn,
                                                    const int* __restrict__ dstn,
                                                    const int* __restrict__ bhist,
                                                    int* __restrict__ gcur,
                                                    unsigned long long* __restrict__ ebuf) {
  __shared__ int sbuf[512];
  __shared__ int boff[NB];
  __shared__ int hist[NB];
  __shared__ int base[NB];
  int t = threadIdx.x;
  int v = (t < NB) ? bhist[t] : 0;
  int incl = scan_incl_512(v, sbuf);
  if (t < NB) { boff[t] = incl - v; hist[t] = 0; }
  __syncthreads();
  int e0 = blockIdx.x * EPB;
  for (int i = t; i < EPB; i += 512)
    atomicAdd(&hist[dstn[e0 + i] >> 7], 1);
  __syncthreads();
  for (int i = t; i < NB; i += 512) {
    int c = hist[i];
    base[i] = c ? (boff[i] + atomicAdd(&gcur[i], c)) : 0;
  }
  __syncthreads();
  for (int i = t; i < EPB; i += 512) {
    int s = srcn[e0 + i], d = dstn[e0 + i];
    int b = d >> 7;
    int pos = atomicSub(&hist[b], 1) - 1;   // order within slice irrelevant
    ebuf[(size_t)base[b] + pos] = ((unsigned long long)(unsigned)d << 32) | (unsigned)s;
  }
}

// ---------------- per-bucket counting sort -> CSR (scan inlined) ---------------
__global__ __launch_bounds__(512) void bfill_kernel(const unsigned long long* __restrict__ ebuf,
                                                    const int* __restrict__ bhist,
                                                    int* __restrict__ rowoff,
                                                    int* __restrict__ csr) {
  __shared__ int sbuf[512];
  __shared__ int sb[2];
  __shared__ int ndeg[128], noff[128];
  int b = blockIdx.x;
  int t = threadIdx.x;
  int v = (t < NB) ? bhist[t] : 0;
  int incl = scan_incl_512(v, sbuf);
  if (t == b) { sb[0] = incl - v; sb[1] = v; }
  if (t < 128) ndeg[t] = 0;
  __syncthreads();
  int bo = sb[0], cnt = sb[1];
  for (int i = t; i < cnt; i += 512)
    atomicAdd(&ndeg[(int)(ebuf[bo + i] >> 32) & 127], 1);
  __syncthreads();
  if (t < 128) noff[t] = ndeg[t];
  __syncthreads();
  for (int off = 1; off < 128; off <<= 1) {   // inclusive scan (Hillis-Steele)
    int x = 0;
    if (t < 128 && t >= off) x = noff[t - off];
    __syncthreads();
    if (t < 128 && t >= off) noff[t] += x;
    __syncthreads();
  }
  if (t < 128) {
    int ex = noff[t] - ndeg[t];    // exclusive
    noff[t] = ex;
    int node = b * 128 + t;
    if (node < NN) rowoff[node] = bo + ex;
  }
  if (b == NB - 1 && t == 0) rowoff[NN] = NE;
  __syncthreads();
  for (int i = t; i < cnt; i += 512) {
    unsigned long long e = ebuf[bo + i];
    int dl = (int)(e >> 32) & 127;
    int pos = atomicSub(&ndeg[dl], 1) - 1;
    csr[bo + noff[dl] + pos] = (int)(unsigned)e;
  }
}

// ---------------- fused setup: convz (6250 blocks) | prep (64) | bhist (128) ----
__global__ __launch_bounds__(256) void setup_kernel(
    const float* __restrict__ z, unsigned short* __restrict__ A1,
    const float* __restrict__ w1n, const float* __restrict__ w1r,
    const float* __restrict__ w2n, const float* __restrict__ w2r,
    const float* __restrict__ wfn, const float* __restrict__ wfr,
    const float* __restrict__ wr1, const float* __restrict__ wr2,
    unsigned short* __restrict__ Bp1, unsigned short* __restrict__ Bp2,
    unsigned short* __restrict__ Bp3,
    const int* __restrict__ dstn, int* __restrict__ bhist) {
  __shared__ int h[NB];
  int b = blockIdx.x;
  if (b < 6250) {               // ---- convz: z (f32) -> bf16 into A1 right half
    int i = b * 256 + threadIdx.x;
    if (i >= NN * 128 / 4) return;
    int i4 = i * 4;
    int row = i4 >> 7, c = i4 & 127;
    f32x4 v = *(const f32x4*)(z + i4);
    us4 o = { f2bf(v[0]), f2bf(v[1]), f2bf(v[2]), f2bf(v[3]) };
    *(us4*)(A1 + (size_t)row * 256 + 128 + c) = o;
  } else if (b < 6314) {        // ---- prep: pack B into MFMA fragment-major
    int g = (b - 6250) * 256 + threadIdx.x;
    unsigned short* D; int NT, fi;
    int which;  // 1,2,3
    if      (g < 10240) { fi = g;         D = Bp1; NT = 20; which = 1; }
    else if (g < 14336) { fi = g - 10240; D = Bp2; NT = 8;  which = 2; }
    else if (g < 16384) { fi = g - 14336; D = Bp3; NT = 4;  which = 3; }
    else return;
    int lane = fi & 63, t = fi >> 6;
    int nt = t % NT, k0i = t / NT;
    int m = lane & 15, q = lane >> 4;
    int kb = k0i * 32 + q * 8;          // 8-aligned: all j on same side of 128
    int n = nt * 16 + m;
    int hi = (kb >= 128);
    int k0_ = kb - (hi ? 128 : 0);
    const float* W = nullptr; int Nseg = 128; int nn = n;
    if (which == 1) {
      if (n < 128)      { W = hi ? w1r : w1n; nn = n; Nseg = 128; }
      else if (n < 256) { W = hi ? wr1 : nullptr; nn = n - 128; Nseg = 128; }
      else              { W = hi ? wr2 : nullptr; nn = n - 256; Nseg = 64; }
    } else if (which == 2) { W = hi ? w2r : w2n; Nseg = 128; }
    else                   { W = hi ? wfr : wfn; Nseg = 64; }
    unsigned short o[8];
#pragma unroll
    for (int j = 0; j < 8; j++)
      o[j] = W ? f2bf(W[(size_t)(k0_ + j) * Nseg + nn]) : (unsigned short)0;
    *(us8*)(D + (size_t)fi * 8) = *(const us8*)o;
  } else {                      // ---- bhist
    for (int i = threadIdx.x; i < NB; i += 256) h[i] = 0;
    __syncthreads();
    int e0 = (b - 6314) * EPB;
    for (int i = threadIdx.x; i < EPB; i += 256)
      atomicAdd(&h[dstn[e0 + i] >> 7], 1);
    __syncthreads();
    for (int i = threadIdx.x; i < NB; i += 256)
      if (h[i]) atomicAdd(&bhist[i], h[i]);
  }
}

// ---------------- mean aggregation: one wave per node, packed f32x2 math -------
__device__ __forceinline__ void agg_wave(const unsigned short* __restrict__ feat,
                                         unsigned short* __restrict__ outm,
                                         const int* __restrict__ rowoff,
                                         const int* __restrict__ csr, int node) {
  int lane = threadIdx.x & 63;
  int g = lane >> 4;           // neighbor subgroup 0..3
  int c = (lane & 15) << 3;    // column offset (8 bf16 = 16B per lane)
  int beg = rowoff[node], end = rowoff[node + 1];
  f32x2 a[4];
#pragma unroll
  for (int k = 0; k < 4; ++k) a[k] = (f32x2){0.f, 0.f};
  int e1 = end - 1;
  for (int j = beg + g; j < end; j += 16) {
    int j1 = (j + 4 < e1) ? j + 4 : e1;
    int j2 = (j + 8 < e1) ? j + 8 : e1;
    int j3 = (j + 12 < e1) ? j + 12 : e1;
    int s0 = csr[j], s1 = csr[j1], s2 = csr[j2], s3 = csr[j3];
    float w1 = (j + 4 < end) ? 1.f : 0.f;
    float w2 = (j + 8 < end) ? 1.f : 0.f;
    float w3 = (j + 12 < end) ? 1.f : 0.f;
    u32x4 v0 = *(const u32x4*)(feat + (size_t)s0 * 256 + c);
    u32x4 v1 = *(const u32x4*)(feat + (size_t)s1 * 256 + c);
    u32x4 v2 = *(const u32x4*)(feat + (size_t)s2 * 256 + c);
    u32x4 v3 = *(const u32x4*)(feat + (size_t)s3 * 256 + c);
#pragma unroll
    for (int k = 0; k < 4; ++k) {
      a[k] += (f32x2){u2f(v0[k] << 16), u2f(v0[k] & 0xffff0000u)};
      a[k] += (f32x2){u2f(v1[k] << 16), u2f(v1[k] & 0xffff0000u)} * w1;
      a[k] += (f32x2){u2f(v2[k] << 16), u2f(v2[k] & 0xffff0000u)} * w2;
      a[k] += (f32x2){u2f(v3[k] << 16), u2f(v3[k] & 0xffff0000u)} * w3;
    }
  }
#pragma unroll
  for (int k = 0; k < 4; ++k)
#pragma unroll
    for (int h2 = 0; h2 < 2; ++h2) {
      a[k][h2] += __shfl_xor(a[k][h2], 16, 64);
      a[k][h2] += __shfl_xor(a[k][h2], 32, 64);
    }
  if (g == 0) {
    float inv = 1.f / fmaxf((float)(end - beg), 1.f);
    unsigned int o[4];
#pragma unroll
    for (int k = 0; k < 4; ++k)
      o[k] = ((unsigned int)f2bf(a[k][1] * inv) << 16) | f2bf(a[k][0] * inv);
    *(u32x4*)(outm + (size_t)node * 256 + c) = *(const u32x4*)o;
  }
}

__global__ __launch_bounds__(512, 8) void agg_kernel(unsigned short* __restrict__ A,
                                                     const int* __restrict__ rowoff,
                                                     const int* __restrict__ csr) {
  int node = blockIdx.x * 8 + (threadIdx.x >> 6);
  agg_wave(A + 128, A, rowoff, csr, node);
}

// ---------------- agg1 + res gemm merged: blocks <6250 gather, rest MFMA -------
__global__ __launch_bounds__(512, 8) void aggres1_kernel(
    unsigned short* __restrict__ A1,
    const unsigned short* __restrict__ Bp1,
    const float* __restrict__ br1, const float* __restrict__ br2,
    const int* __restrict__ rowoff, const int* __restrict__ csr,
    unsigned short* __restrict__ res1, unsigned short* __restrict__ res2) {
  int bx = blockIdx.x;
  if (bx < 6250) {
    int node = bx * 8 + (threadIdx.x >> 6);
    agg_wave(A1 + 128, A1, rowoff, csr, node);
    return;
  }
  int b = bx - 6250;                 // 0..781
  int chunk = (b >= NB);             // 0: tiles 8..13, 1: tiles 14..19
  int bb = b - chunk * NB;
  int tid = threadIdx.x;
  int w = tid >> 6, lane = tid & 63;
  int m = lane & 15, q = lane >> 4;
  int row = bb * 128 + w * 16 + m;
  const unsigned short* ar = A1 + (size_t)row * 256 + 128 + q * 8;
  bf16x8 af[4];
#pragma unroll
  for (int k = 0; k < 4; ++k) af[k] = *(const bf16x8*)(ar + k * 32);
  f32x4 acc[6];
#pragma unroll
  for (int t = 0; t < 6; ++t) acc[t] = (f32x4){0.f, 0.f, 0.f, 0.f};
#pragma unroll
  for (int k0i = 0; k0i < 4; ++k0i)
#pragma unroll
    for (int t = 0; t < 6; ++t)
      acc[t] = __builtin_amdgcn_mfma_f32_16x16x32_bf16(
          bfrag(Bp1, (k0i + 4) * 20 + 8 + chunk * 6 + t, lane), af[k0i], acc[t], 0, 0, 0);
  int src0 = m + ((q & 1) ? 32 : 0);
#pragma unroll
  for (int pl = 0; pl < 3; ++pl) {
    int P = chunk * 3 + pl;
    const float* bias; unsigned short* dst; int dstride, colb;
    if (P < 4) { bias = br1 + 32 * P;       dst = res1; dstride = 128; colb = 32 * P; }
    else       { bias = br2 + 32 * (P - 4); dst = res2; dstride = 64;  colb = 32 * (P - 4); }
    f32x4 v0 = acc[2 * pl], v1 = acc[2 * pl + 1];
    f32x4 bb0 = *(const f32x4*)(bias + 4 * q);
    f32x4 bb1 = *(const f32x4*)(bias + 16 + 4 * q);
#pragma unroll
    for (int r = 0; r < 4; ++r) { v0[r] += bb0[r]; v1[r] += bb1[r]; }
    unsigned long long d0 = pk64(v0), d1 = pk64(v1);
    unsigned long long a0 = __shfl(d0, src0, 64);
    unsigned long long b0 = __shfl(d0, src0 + 16, 64);
    unsigned long long a1 = __shfl(d1, src0, 64);
    unsigned long long b1v = __shfl(d1, src0 + 16, 64);
    unsigned long long lo = (q >> 1) ? a1 : a0;
    unsigned long long hi = (q >> 1) ? b1v : b0;
    unsigned long long ov[2] = { lo, hi };
    *(us8*)(dst + (size_t)row * dstride + colb + 8 * q) = *(const us8*)ov;  // res padded NNP
  }
}

// ---------------- gemm1h: [mean1|z] @ W1-pack tiles 0..7 -> h1 (A2 right) ------
__global__ __launch_bounds__(256, 4) void gemm1h_kernel(
    const unsigned short* __restrict__ A1,
    const unsigned short* __restrict__ Bp1,
    const float* __restrict__ b1,
    unsigned short* __restrict__ A2) {
  int tid = threadIdx.x;
  int w = tid >> 6, lane = tid & 63;
  int m = lane & 15, q = lane >> 4;
  int row = blockIdx.x * 64 + w * 16 + m;
  const unsigned short* ar = A1 + (size_t)row * 256 + q * 8;
  bf16x8 af[8];
#pragma unroll
  for (int k = 0; k < 8; ++k) af[k] = *(const bf16x8*)(ar + k * 32);
  f32x4 acc[8];
#pragma unroll
  for (int t = 0; t < 8; ++t) acc[t] = (f32x4){0.f, 0.f, 0.f, 0.f};
#pragma unroll
  for (int k0i = 0; k0i < 8; ++k0i)
#pragma unroll
    for (int t = 0; t < 8; ++t)
      acc[t] = __builtin_amdgcn_mfma_f32_16x16x32_bf16(
          bfrag(Bp1, k0i * 20 + t, lane), af[k0i], acc[t], 0, 0, 0);
  int src0 = m + ((q & 1) ? 32 : 0);
#pragma unroll
  for (int p = 0; p < 4; ++p) {
    f32x4 v0 = acc[2 * p], v1 = acc[2 * p + 1];
    f32x4 bb0 = *(const f32x4*)(b1 + 32 * p + 4 * q);
    f32x4 bb1 = *(const f32x4*)(b1 + 32 * p + 16 + 4 * q);
#pragma unroll
    for (int r = 0; r < 4; ++r) {
      v0[r] = fmaxf(v0[r] + bb0[r], 0.f);
      v1[r] = fmaxf(v1[r] + bb1[r], 0.f);
    }
    unsigned long long d0 = pk64(v0), d1 = pk64(v1);
    unsigned long long a0 = __shfl(d0, src0, 64);
    unsigned long long b0 = __shfl(d0, src0 + 16, 64);
    unsigned long long a1 = __shfl(d1, src0, 64);
    unsigned long long b1v = __shfl(d1, src0 + 16, 64);
    unsigned long long lo = (q >> 1) ? a1 : a0;
    unsigned long long hi = (q >> 1) ? b1v : b0;
    unsigned long long ov[2] = { lo, hi };
    *(us8*)(A2 + (size_t)row * 256 + 128 + 32 * p + 8 * q) = *(const us8*)ov;
  }
}

// ---------------- gemm2: [mean2|h1] @ W2 + res1 -> h2 (A1 right); fused y3 -----
// y3 = h2 @ wfn (mean-side tiles of Bp3): A-frags are exactly the epilogue's ov
// bytes. y3 lands in A1 left half cols 64..127 (dead region).
__global__ __launch_bounds__(256, 4) void gemm2_kernel(
    const unsigned short* __restrict__ A2,
    const unsigned short* __restrict__ Bp2,
    const unsigned short* __restrict__ Bp3,
    const float* __restrict__ b2,
    const unsigned short* __restrict__ res1,
    unsigned short* __restrict__ A1out) {
  int tid = threadIdx.x;
  int w = tid >> 6, lane = tid & 63;
  int m = lane & 15, q = lane >> 4;
  int row = blockIdx.x * 64 + w * 16 + m;
  const unsigned short* ar = A2 + (size_t)row * 256 + q * 8;
  bf16x8 af[8];
#pragma unroll
  for (int k = 0; k < 8; ++k) af[k] = *(const bf16x8*)(ar + k * 32);
  f32x4 acc[8];
#pragma unroll
  for (int t = 0; t < 8; ++t) acc[t] = (f32x4){0.f, 0.f, 0.f, 0.f};
#pragma unroll
  for (int k0i = 0; k0i < 8; ++k0i)
#pragma unroll
    for (int t = 0; t < 8; ++t)
      acc[t] = __builtin_amdgcn_mfma_f32_16x16x32_bf16(
          bfrag(Bp2, k0i * 8 + t, lane), af[k0i], acc[t], 0, 0, 0);
  int src0 = m + ((q & 1) ? 32 : 0);
  bf16x8 afy[4];
#pragma unroll
  for (int p = 0; p < 4; ++p) {
    f32x4 v0 = acc[2 * p], v1 = acc[2 * p + 1];
    f32x4 bb0 = *(const f32x4*)(b2 + 32 * p + 4 * q);
    f32x4 bb1 = *(const f32x4*)(b2 + 32 * p + 16 + 4 * q);
#pragma unroll
    for (int r = 0; r < 4; ++r) {
      v0[r] = fmaxf(v0[r] + bb0[r], 0.f);
      v1[r] = fmaxf(v1[r] + bb1[r], 0.f);
    }
    unsigned long long d0 = pk64(v0), d1 = pk64(v1);
    unsigned long long a0 = __shfl(d0, src0, 64);
    unsigned long long b0 = __shfl(d0, src0 + 16, 64);
    unsigned long long a1 = __shfl(d1, src0, 64);
    unsigned long long b1v = __shfl(d1, src0 + 16, 64);
    unsigned long long lo = (q >> 1) ? a1 : a0;
    unsigned long long hi = (q >> 1) ? b1v : b0;
    size_t off = 32 * p + 8 * q;
    us8 rv = *(const us8*)(res1 + (size_t)row * 128 + off);   // res1 padded NNP
    unsigned long long ov[2] = { lo, hi };
    unsigned short* e = (unsigned short*)ov;
#pragma unroll
    for (int r = 0; r < 8; ++r) e[r] = f2bf(bf2f(e[r]) + bf2f(rv[r]));
    *(us8*)(A1out + (size_t)row * 256 + 128 + off) = *(const us8*)ov;
    afy[p] = *(const bf16x8*)ov;        // h2 fragment for y3 (k0i = p)
  }
  // y3 = h2 @ wfn : mean-side tiles of Bp3 (k0i*4 + t, k0i=0..3, t=0..3)
  f32x4 accy[4];
#pragma unroll
  for (int t = 0; t < 4; ++t) accy[t] = (f32x4){0.f, 0.f, 0.f, 0.f};
#pragma unroll
  for (int p = 0; p < 4; ++p)
#pragma unroll
    for (int t = 0; t < 4; ++t)
      accy[t] = __builtin_amdgcn_mfma_f32_16x16x32_bf16(
          bfrag(Bp3, p * 4 + t, lane), afy[p], accy[t], 0, 0, 0);
#pragma unroll
  for (int py = 0; py < 2; ++py) {
    f32x4 v0 = accy[2 * py], v1 = accy[2 * py + 1];
    unsigned long long d0 = pk64(v0), d1 = pk64(v1);
    unsigned long long a0 = __shfl(d0, src0, 64);
    unsigned long long b0 = __shfl(d0, src0 + 16, 64);
    unsigned long long a1 = __shfl(d1, src0, 64);
    unsigned long long b1v = __shfl(d1, src0 + 16, 64);
    unsigned long long lo = (q >> 1) ? a1 : a0;
    unsigned long long hi = (q >> 1) ? b1v : b0;
    unsigned long long ov[2] = { lo, hi };
    *(us8*)(A1out + (size_t)row * 256 + 64 + 32 * py + 8 * q) = *(const us8*)ov;
  }
}

// ---------------- fused agg64 + gemm3: gather mean3y to LDS, then root gemm ----
// 782 blocks x 4 waves. Wave w gathers 16 nodes (128B y3 rows) into LDS, then
// MFMAs the root-side gemm3 for its own 16 rows + epilogue adds from LDS.
__global__ __launch_bounds__(256, 4) void aggemm3_kernel(
    const unsigned short* __restrict__ A1,
    const unsigned short* __restrict__ Bp3,
    const float* __restrict__ bias,
    const int* __restrict__ rowoff, const int* __restrict__ csr,
    const unsigned short* __restrict__ res2,
    float* __restrict__ out_f) {
  __shared__ unsigned short meanS[64 * 64];   // 8 KB
  int tid = threadIdx.x;
  int w = tid >> 6, lane = tid & 63;
  int row0 = blockIdx.x * 64;
  // ---- phase 1: gather y3 (A1 left, cols 64..127) -> meanS
  {
    const unsigned short* feat = A1 + 64;
    int g = lane >> 3;          // neighbor subgroup 0..7
    int c = (lane & 7) << 3;    // column offset (8 bf16 = 16B per lane)
    for (int i = 0; i < 16; ++i) {
      int node = row0 + w * 16 + i;
      int beg = 0, end = 0;
      if (node < NN) { beg = rowoff[node]; end = rowoff[node + 1]; }
      f32x2 a[4];
#pragma unroll
      for (int k = 0; k < 4; ++k) a[k] = (f32x2){0.f, 0.f};
      int e1 = end - 1 > beg ? end - 1 : beg;
      for (int j = beg + g; j < end; j += 32) {
        int j1 = (j + 8  < e1) ? j + 8  : e1;
        int j2 = (j + 16 < e1) ? j + 16 : e1;
        int j3 = (j + 24 < e1) ? j + 24 : e1;
        int s0 = csr[j], s1 = csr[j1], s2 = csr[j2], s3 = csr[j3];
        float w1 = (j + 8  < end) ? 1.f : 0.f;
        float w2 = (j + 16 < end) ? 1.f : 0.f;
        float w3 = (j + 24 < end) ? 1.f : 0.f;
        u32x4 v0 = *(const u32x4*)(feat + (size_t)s0 * 256 + c);
        u32x4 v1 = *(const u32x4*)(feat + (size_t)s1 * 256 + c);
        u32x4 v2 = *(const u32x4*)(feat + (size_t)s2 * 256 + c);
        u32x4 v3 = *(const u32x4*)(feat + (size_t)s3 * 256 + c);
#pragma unroll
        for (int k = 0; k < 4; ++k) {
          a[k] += (f32x2){u2f(v0[k] << 16), u2f(v0[k] & 0xffff0000u)};
          a[k] += (f32x2){u2f(v1[k] << 16), u2f(v1[k] & 0xffff0000u)} * w1;
          a[k] += (f32x2){u2f(v2[k] << 16), u2f(v2[k] & 0xffff0000u)} * w2;
          a[k] += (f32x2){u2f(v3[k] << 16), u2f(v3[k] & 0xffff0000u)} * w3;
        }
      }
#pragma unroll
      for (int k = 0; k < 4; ++k)
#pragma unroll
        for (int h2 = 0; h2 < 2; ++h2) {
          a[k][h2] += __shfl_xor(a[k][h2], 8, 64);
          a[k][h2] += __shfl_xor(a[k][h2], 16, 64);
          a[k][h2] += __shfl_xor(a[k][h2], 32, 64);
        }
      if (g == 0) {
        float inv = 1.f / fmaxf((float)(end - beg), 1.f);
        unsigned int o[4];
#pragma unroll
        for (int k = 0; k < 4; ++k)
          o[k] = ((unsigned int)f2bf(a[k][1] * inv) << 16) | f2bf(a[k][0] * inv);
        *(u32x4*)(meanS + (size_t)(w * 16 + i) * 64 + c) = *(const u32x4*)o;
      }
    }
  }
  __syncthreads();
  // ---- phase 2: gemm3 root side + epilogue
  int m = lane & 15, q = lane >> 4;
  int row = row0 + w * 16 + m;
  const unsigned short* ar = A1 + (size_t)row * 256 + 128 + q * 8;   // h2
  bf16x8 af[4];
#pragma unroll
  for (int k = 0; k < 4; ++k) af[k] = *(const bf16x8*)(ar + k * 32);
  f32x4 acc[4];
#pragma unroll
  for (int t = 0; t < 4; ++t) acc[t] = (f32x4){0.f, 0.f, 0.f, 0.f};
#pragma unroll
  for (int k0i = 0; k0i < 4; ++k0i)
#pragma unroll
    for (int t = 0; t < 4; ++t)
      acc[t] = __builtin_amdgcn_mfma_f32_16x16x32_bf16(
          bfrag(Bp3, (k0i + 4) * 4 + t, lane), af[k0i], acc[t], 0, 0, 0);
  if (row >= NN) return;
  int cb = q * 4;
#pragma unroll
  for (int s = 0; s < 4; ++s) {
    int col = s * 16 + cb;
    f32x4 v = acc[s];
    f32x4 bb = *(const f32x4*)(bias + col);
    us4 rv = *(const us4*)(res2 + (size_t)row * 64 + col);
    us4 mv = *(const us4*)(meanS + (size_t)(w * 16 + m) * 64 + col);
#pragma unroll
    for (int r = 0; r < 4; ++r) v[r] += bb[r] + bf2f(rv[r]) + bf2f(mv[r]);
    if (col < 8) {
#pragma unroll
      for (int r = 0; r < 4; ++r) v[r] = 1.f / (1.f + __expf(-v[r]));
    }
    *(f32x4*)(out_f + (size_t)row * 64 + col) = v;
  }
}

extern "C" void kernel_launch(void* const* d_in, const int* in_sizes, int n_in,
                              void* d_out, int out_size, void* d_ws, size_t ws_size,
                              hipStream_t stream) {
  const float* z   = (const float*)d_in[0];
  const int*   edge = (const int*)d_in[1];
  const int*   srcn = edge;        // edge_index[0]
  const int*   dstn = edge + NE;   // edge_index[1]
  const float* w1n = (const float*)d_in[2];
  const float* w1r = (const float*)d_in[3];
  const float* b1  = (const float*)d_in[4];
  const float* w2n = (const float*)d_in[5];
  const float* w2r = (const float*)d_in[6];
  const float* b2  = (const float*)d_in[7];
  const float* wfn = (const float*)d_in[8];
  const float* wfr = (const float*)d_in[9];
  const float* bfb = (const float*)d_in[10];
  const float* wr1 = (const float*)d_in[11];
  const float* br1 = (const float*)d_in[12];
  const float* wr2 = (const float*)d_in[13];
  const float* br2 = (const float*)d_in[14];
  float* out = (float*)d_out;

  char* p = (char*)d_ws;
  auto alloc = [&](size_t bytes) { char* r = p; p += (bytes + 255) & ~255ull; return r; };
  int* rowoff = (int*)alloc((size_t)(NN + 1) * 4);
  int* bhist  = (int*)alloc((size_t)2 * NB * 4);
  int* gcur   = bhist + NB;
  int* csr    = (int*)alloc((size_t)NE * 4);
  unsigned short* A1 = (unsigned short*)alloc((size_t)NNP * 256 * 2);  // [mean1|z] -> [.,y3|h2]
  unsigned short* A2 = (unsigned short*)alloc((size_t)NNP * 256 * 2);  // [mean2|h1]
  unsigned short* res1 = (unsigned short*)alloc((size_t)NNP * 128 * 2);
  unsigned short* res2 = (unsigned short*)alloc((size_t)NNP * 64 * 2);
  unsigned short* Bp1 = (unsigned short*)alloc(10240 * 8 * 2);
  unsigned short* Bp2 = (unsigned short*)alloc(4096 * 8 * 2);
  unsigned short* Bp3 = (unsigned short*)alloc(2048 * 8 * 2);
  // ebuf aliases res1 (6.4 MB <= 12.8 MB): dead before aggres1 writes res1
  unsigned long long* ebuf = (unsigned long long*)res1;

  hipMemsetAsync(bhist, 0, (size_t)2 * NB * 4, stream);   // bhist + gcur
  // fused prologue: convz | prep | bhist
  setup_kernel<<<6442, 256, 0, stream>>>(z, A1, w1n, w1r, w2n, w2r, wfn, wfr, wr1, wr2,
                                         Bp1, Bp2, Bp3, dstn, bhist);
  bscat_kernel<<<128, 512, 0, stream>>>(srcn, dstn, bhist, gcur, ebuf);
  bfill_kernel<<<NB, 512, 0, stream>>>(ebuf, bhist, rowoff, csr);

  const int ggemm = NNP / 64;   // 782

  // layer 1: gather(z) || res1/res2 root-gemm, then h1
  aggres1_kernel<<<6250 + 2 * NB, 512, 0, stream>>>(A1, Bp1, br1, br2, rowoff, csr, res1, res2);
  gemm1h_kernel<<<ggemm, 256, 0, stream>>>(A1, Bp1, b1, A2);

  // layer 2: gather(h1); gemm2 writes h2 + fused y3 = h2@wfn
  agg_kernel<<<6250, 512, 0, stream>>>(A2, rowoff, csr);
  gemm2_kernel<<<ggemm, 256, 0, stream>>>(A2, Bp2, Bp3, b2, res1, A1);

  // layer 3: fused 64-col gather of y3 + root gemm + adds (one kernel)
  aggemm3_kernel<<<ggemm, 256, 0, stream>>>(A1, Bp3, bfb, rowoff, csr, res2, out);
}